// Round 9
// baseline (116.480 us; speedup 1.0000x reference)
//
#include <hip/hip_runtime.h>
#include <hip/hip_fp16.h>

#define P_DIM 1024
#define H_DIM 256
#define L_DIM 16384
#define DT 0.001f
#define TWOPI 6.283185307179586f
#define INV2PI 0.15915494309189535f
#define WSCALE 4096.0f
#define INV_WSCALE (1.0f / 4096.0f)
#define BM 256
#define BN 128
#define BK 64
#define NT 512
// L-fold: out[h][c*8192+l] = sum_p (W[h][p]*D[p]^c) V[p][l], D = A_bar^8192
#define LHALF 8192.0f

typedef _Float16 f16x8 __attribute__((ext_vector_type(8)));
typedef float f32x4 __attribute__((ext_vector_type(4)));

#define GPTR(p) (const __attribute__((address_space(1))) unsigned*)(p)
#define LPTR(p) (__attribute__((address_space(3))) unsigned*)(p)

union H2U { __half2 h; unsigned u; };

__device__ __forceinline__ float2 cmulf(float2 a, float2 b) {
    return make_float2(a.x * b.x - a.y * b.y, a.x * b.y + a.y * b.x);
}

// ---------- prep: W2big[c][h][p] = C[h,p]*scale(p)*B[p,h]*4096 * D(p)^c ----------
__global__ __launch_bounds__(256)
void prep_kernel(const float* __restrict__ Ag, const float* __restrict__ Bg,
                 const float* __restrict__ Cg, __half* __restrict__ W2) {
    __shared__ float2 Bt[64][33];   // [p][h] tile, padded
    __shared__ float2 sc[64];
    __shared__ float2 dl[64];       // D[p] = A_bar[p]^8192
    const int t  = threadIdx.x;
    const int p0 = (blockIdx.x & 15) << 6;   // 16 p-blocks of 64
    const int h0 = (blockIdx.x >> 4) << 5;   // 8 h-blocks of 32

    if (t < 64) {
        float2 a = ((const float2*)Ag)[p0 + t];
        float er = __expf(a.x * DT);
        float s, c; __sincosf(a.y * DT, &s, &c);
        float nr = er * c - 1.f, ni = er * s;
        float inv = 1.f / (a.x * a.x + a.y * a.y);
        sc[t] = make_float2((nr * a.x + ni * a.y) * inv, (ni * a.x - nr * a.y) * inv);
        // D = exp(A * DT * 8192): magnitude exp(Ar*8.192), phase Ai*8.192 (mod 2pi)
        float em = __expf(a.x * (DT * LHALF));
        float rev = a.y * (DT * LHALF * INV2PI); rev -= rintf(rev);
        float ds, dc; __sincosf(rev * TWOPI, &ds, &dc);
        dl[t] = make_float2(em * dc, em * ds);
    }
    #pragma unroll
    for (int i = 0; i < 8; ++i) {           // B: (p,h) layout, h fastest -> coalesced
        int idx = i * 256 + t, p = idx >> 5, h = idx & 31;
        Bt[p][h] = ((const float2*)Bg)[(size_t)(p0 + p) * H_DIM + h0 + h];
    }
    __syncthreads();
    #pragma unroll
    for (int i = 0; i < 8; ++i) {           // C: (h,p) layout, p fastest -> coalesced
        int idx = i * 256 + t, h = idx >> 6, p = idx & 63;
        float2 cc = ((const float2*)Cg)[(size_t)(h0 + h) * P_DIM + p0 + p];
        float2 s2 = sc[p], b = Bt[p][h];
        float2 tv = cmulf(cc, s2);
        float2 w0 = make_float2((tv.x * b.x - tv.y * b.y) * WSCALE,
                                (tv.x * b.y + tv.y * b.x) * WSCALE);
        float2 w1 = cmulf(w0, dl[p]);
        ((__half2*)W2)[(size_t)(h0 + h) * P_DIM + p0 + p] =
            __float22half2_rn(w0);
        ((__half2*)W2)[(size_t)(256 + h0 + h) * P_DIM + p0 + p] =
            __float22half2_rn(w1);
    }
}

// ---------- main: L-folded GEMM, 256x128 tile, 1 block/CU, r2 cadence ----------
__global__ __launch_bounds__(NT, 2)
void vand_mfma_kernel(const float* __restrict__ Ag,
                      const _Float16* __restrict__ W2,
                      float* __restrict__ out) {
    __shared__ __attribute__((aligned(16))) _Float16 As[2][BM * BK];  // 2x32KB, XOR (DMA)
    __shared__ __attribute__((aligned(16))) _Float16 Bs[2][BN * BK];  // 2x16KB, XOR (VALU)
    __shared__ float4 Atab[P_DIM];   // 16KB: (abar_re, abar_im, cx, cy) per p
    // total 112KB -> 1 block/CU, 8 waves

    const int tid  = threadIdx.x;
    const int lane = tid & 63;
    const int w    = tid >> 6;           // 0..7
    const int wm   = w & 3, wn = w >> 2; // 4M x 2N waves, wave tile 64x64
    const int cfold = blockIdx.y;        // 0 or 1: which L-half
    const int nb   = blockIdx.x * BN;    // float col within half
    const int lb   = blockIdx.x * (BN / 2);

    const float2* Ag2 = (const float2*)Ag;

    // ---- Atab: A_bar and anchor coeffs per p, once per block ----
    #pragma unroll
    for (int i = 0; i < 2; ++i) {
        int p = tid + i * 512;
        float2 a = Ag2[p];
        float e = __expf(a.x * DT);
        float s, c; __sincosf(a.y * DT, &s, &c);
        Atab[p] = make_float4(e * c, e * s, a.x * DT, a.y * (DT * INV2PI));
    }

    f32x4 acc[4][4];
    #pragma unroll
    for (int mt = 0; mt < 4; ++mt)
        #pragma unroll
        for (int nt = 0; nt < 4; ++nt)
            acc[mt][nt] = (f32x4){0.f, 0.f, 0.f, 0.f};

    // V-gen mapping (r5-verified, NT=512): 1 p x 4 l per thread
    const int pl    = tid & 31;                  // p within 32-wide chunk
    const int lg    = tid >> 5;                  // l-group 0..15 (4 complex l each)
    const float l0f = (float)(lb + lg * 4);
    const int cq3   = (pl >> 2) << 3;
    const int cs    = (2 * pl) & 7;
    const int vbase = lg * 512 + cs;

    // DMA mapping (r2-verified): per wave 32 rows of W-table
    const int goff = (lane >> 3) * 2048 + (((lane & 7) ^ (lane >> 3)) << 3);
    const _Float16* gwbase = W2 + (size_t)(cfold * 256 + (w << 5)) * 2048;
    const int ldsoff = (w << 5) * 64;

    _Float16* Acur = &As[0][0]; _Float16* Bcur = &Bs[0][0];
    _Float16* Anxt = &As[1][0]; _Float16* Bnxt = &Bs[1][0];

#define DMA_CHUNK(K0, DST)                                                        \
    {                                                                             \
        const _Float16* gw = gwbase + (K0) + goff;                                \
        _Float16* lB = (DST) + ldsoff;                                            \
        _Pragma("unroll")                                                         \
        for (int r = 0; r < 4; ++r)                                               \
            __builtin_amdgcn_global_load_lds(GPTR(gw + r * 8 * 2048),             \
                                             LPTR(lB + r * 8 * 64), 16, 0, 0);    \
    }

#define VGEN_CHUNK(K0, DST)                                                       \
    {                                                                             \
        const int pg = ((K0) >> 1) + pl;                                          \
        float4 t4 = Atab[pg];                                                     \
        float mg = __expf(t4.z * l0f);                                            \
        float x  = t4.w * l0f; x -= rintf(x);                                     \
        float s, c; __sincosf(x * TWOPI, &s, &c);                                 \
        float2 v  = make_float2(mg * c, mg * s);                                  \
        float2 ab = make_float2(t4.x, t4.y);                                      \
        _Pragma("unroll")                                                         \
        for (int j = 0; j < 4; ++j) {                                             \
            H2U u0, u1;                                                           \
            u0.h = __float22half2_rn(make_float2(v.x, -v.y));                     \
            u1.h = __float22half2_rn(make_float2(v.y, v.x));                      \
            int e0 = vbase + j * 128 + (cq3 ^ (((2 * j) & 7) << 3));              \
            int e1 = vbase + j * 128 + 64 + (cq3 ^ (((2 * j + 1) & 7) << 3));     \
            *(unsigned*)((DST) + e0) = u0.u;                                      \
            *(unsigned*)((DST) + e1) = u1.u;                                      \
            if (j < 3) v = cmulf(v, ab);                                          \
        }                                                                         \
    }

    // prologue: chunk 0
    DMA_CHUNK(0, Acur)
    __syncthreads();                 // Atab + As[0] visible (full drain, once)
    VGEN_CHUNK(0, Bcur)

    for (int kk = 0; kk < 32; ++kk) {
        if (kk < 31) {
            const int k1 = (kk + 1) * BK;
            DMA_CHUNK(k1, Anxt)
            VGEN_CHUNK(k1, Bnxt)
            // own DMA(kk) landed (4 newer loads in flight), own VGEN writes done
            asm volatile("s_waitcnt vmcnt(4) lgkmcnt(0)" ::: "memory");
        } else {
            asm volatile("s_waitcnt vmcnt(0) lgkmcnt(0)" ::: "memory");
        }
        __builtin_amdgcn_sched_barrier(0);
        __builtin_amdgcn_s_barrier();        // all waves: As[kk]+Bs[kk] ready
        __builtin_amdgcn_sched_barrier(0);

        __builtin_amdgcn_s_setprio(1);
        #pragma unroll
        for (int ks = 0; ks < 2; ++ks) {
            f16x8 af[4], bf[4];
            const int g = ks * 4 + (lane >> 4);
            #pragma unroll
            for (int t = 0; t < 4; ++t) {
                int m = wm * 64 + t * 16 + (lane & 15);
                af[t] = *(const f16x8*)(Acur + m * 64 + ((g ^ (m & 7)) << 3));
                int n = wn * 64 + t * 16 + (lane & 15);
                bf[t] = *(const f16x8*)(Bcur + n * 64 + ((g ^ (n & 7)) << 3));
            }
            #pragma unroll
            for (int mt = 0; mt < 4; ++mt)
                #pragma unroll
                for (int nt = 0; nt < 4; ++nt)
                    acc[mt][nt] = __builtin_amdgcn_mfma_f32_16x16x32_f16(
                        af[mt], bf[nt], acc[mt][nt], 0, 0, 0);
        }
        __builtin_amdgcn_s_setprio(0);
        __builtin_amdgcn_sched_barrier(0);
        __builtin_amdgcn_s_barrier();        // protect buffers for next overwrite
        __builtin_amdgcn_sched_barrier(0);

        _Float16* tA = Acur; Acur = Anxt; Anxt = tA;
        _Float16* tB = Bcur; Bcur = Bnxt; Bnxt = tB;
    }

    // epilogue: C/D layout col=lane&15, row=(lane>>4)*4+r
    #pragma unroll
    for (int mt = 0; mt < 4; ++mt) {
        #pragma unroll
        for (int nt = 0; nt < 4; ++nt) {
            int h = wm * 64 + mt * 16 + ((lane >> 4) << 2);          // 0..255
            int n = cfold * 16384 + nb + wn * 64 + nt * 16 + (lane & 15);
            #pragma unroll
            for (int r = 0; r < 4; ++r)
                out[(size_t)(h + r) * 32768 + n] = acc[mt][nt][r] * INV_WSCALE;
        }
    }
#undef DMA_CHUNK
#undef VGEN_CHUNK
}

extern "C" void kernel_launch(void* const* d_in, const int* in_sizes, int n_in,
                              void* d_out, int out_size, void* d_ws, size_t ws_size,
                              hipStream_t stream) {
    const float* A = (const float*)d_in[0];   // (P, 2)
    const float* B = (const float*)d_in[1];   // (P, H, 2)
    const float* C = (const float*)d_in[2];   // (H, P, 2)
    float* out = (float*)d_out;               // (H, L, 2)
    __half* W2 = (__half*)d_ws;               // (2, 256, 2048) fp16, 2 MB

    prep_kernel<<<dim3(128), dim3(256), 0, stream>>>(A, B, C, W2);
    vand_mfma_kernel<<<dim3(L_DIM / BN, 2), dim3(NT), 0, stream>>>(
        A, (const _Float16*)W2, out);
}

// Round 10
// 108.633 us; speedup vs baseline: 1.0722x; 1.0722x over previous
//
#include <hip/hip_runtime.h>
#include <hip/hip_fp16.h>

#define P_DIM 1024
#define H_DIM 256
#define L_DIM 16384
#define DT 0.001f
#define TWOPI 6.283185307179586f
#define INV2PI 0.15915494309189535f
#define WSCALE 4096.0f
#define INV_WSCALE (1.0f / 4096.0f)
#define BM 128
#define BN 128
#define BK 64
#define NT 512   // 4 producer waves + 4 consumer waves

typedef _Float16 f16x8 __attribute__((ext_vector_type(8)));
typedef float f32x4 __attribute__((ext_vector_type(4)));

#define GPTR(p) (const __attribute__((address_space(1))) unsigned*)(p)
#define LPTR(p) (__attribute__((address_space(3))) unsigned*)(p)

union H2U { __half2 h; unsigned u; };

__device__ __forceinline__ float2 cmulf(float2 a, float2 b) {
    return make_float2(a.x * b.x - a.y * b.y, a.x * b.y + a.y * b.x);
}

// ---------- prep: W2[h][p] = C[h,p]*scale(p)*B[p,h] * 4096, fp16 pair ----------
__global__ __launch_bounds__(256)
void prep_kernel(const float* __restrict__ Ag, const float* __restrict__ Bg,
                 const float* __restrict__ Cg, __half* __restrict__ W2) {
    __shared__ float2 Bt[64][33];   // [p][h] tile, padded
    __shared__ float2 sc[64];
    const int t  = threadIdx.x;
    const int p0 = (blockIdx.x & 15) << 6;   // 16 p-blocks of 64
    const int h0 = (blockIdx.x >> 4) << 5;   // 8 h-blocks of 32

    if (t < 64) {
        float2 a = ((const float2*)Ag)[p0 + t];
        float er = __expf(a.x * DT);
        float s, c; __sincosf(a.y * DT, &s, &c);
        float nr = er * c - 1.f, ni = er * s;
        float inv = 1.f / (a.x * a.x + a.y * a.y);
        sc[t] = make_float2((nr * a.x + ni * a.y) * inv, (ni * a.x - nr * a.y) * inv);
    }
    #pragma unroll
    for (int i = 0; i < 8; ++i) {           // B: (p,h) layout, h fastest -> coalesced
        int idx = i * 256 + t, p = idx >> 5, h = idx & 31;
        Bt[p][h] = ((const float2*)Bg)[(size_t)(p0 + p) * H_DIM + h0 + h];
    }
    __syncthreads();
    #pragma unroll
    for (int i = 0; i < 8; ++i) {           // C: (h,p) layout, p fastest -> coalesced
        int idx = i * 256 + t, h = idx >> 6, p = idx & 63;
        float2 cc = ((const float2*)Cg)[(size_t)(h0 + h) * P_DIM + p0 + p];
        float2 s2 = sc[p], b = Bt[p][h];
        float2 tv = cmulf(cc, s2);
        float wr = (tv.x * b.x - tv.y * b.y) * WSCALE;
        float wi = (tv.x * b.y + tv.y * b.x) * WSCALE;
        ((__half2*)W2)[(size_t)(h0 + h) * P_DIM + p0 + p] =
            __float22half2_rn(make_float2(wr, wi));
    }
}

// ---------- main: producer/consumer wave specialization, 1 barrier/chunk ----------
__global__ __launch_bounds__(NT, 4)
void vand_mfma_kernel(const float* __restrict__ Ag,
                      const _Float16* __restrict__ W2,
                      float* __restrict__ out) {
    __shared__ __attribute__((aligned(16))) _Float16 As[2][BM * BK];  // 2x16KB, XOR (DMA)
    __shared__ __attribute__((aligned(16))) _Float16 Bs[2][BN * BK];  // 2x16KB, XOR (VALU)
    __shared__ float4 Atab[P_DIM];   // 16KB
    // total 80KB -> 2 blocks/CU; per SIMD: 2 producer + 2 consumer waves

    const int tid  = threadIdx.x;
    const int lane = tid & 63;
    const int w    = tid >> 6;            // 0..7
    const bool producer = (w < 4);
    const int m0   = blockIdx.y * BM;
    const int nb   = blockIdx.x * BN;
    const int lb   = blockIdx.x * (BN / 2);

    const float2* Ag2 = (const float2*)Ag;

    // ---- Atab: all 512 threads, once per block ----
    #pragma unroll
    for (int i = 0; i < 2; ++i) {
        int p = tid + i * 512;
        float2 a = Ag2[p];
        float e = __expf(a.x * DT);
        float s, c; __sincosf(a.y * DT, &s, &c);
        Atab[p] = make_float4(e * c, e * s, a.x * DT, a.y * (DT * INV2PI));
    }

    // ---- producer mappings (waves 0..3, tid 0..255) ----
    // VGEN (r0-verified, 256 threads): 2 p's x 4 l's per thread, b64 stores
    const int q    = tid & 15;
    const int llq  = (tid >> 4) << 2;
    const float l0f = (float)(lb + llq);
    const int grp  = q >> 1, sub = (q & 1) << 2;
    // DMA (r2-verified): 4 waves x 32 rows
    const int goff = (lane >> 3) * 2048 + (((lane & 7) ^ (lane >> 3)) << 3);
    const _Float16* gwbase = W2 + (size_t)(m0 + (w << 5)) * 2048;
    const int ldsoff = (w << 5) * 64;

    // ---- consumer mappings (waves 4..7) ----
    const int wc = w - 4;
    const int wm = wc & 1, wn = wc >> 1;   // 2M x 2N, wave tile 64x64

    f32x4 acc[4][4];
    #pragma unroll
    for (int mt = 0; mt < 4; ++mt)
        #pragma unroll
        for (int nt = 0; nt < 4; ++nt)
            acc[mt][nt] = (f32x4){0.f, 0.f, 0.f, 0.f};

    _Float16* Acur = &As[0][0]; _Float16* Bcur = &Bs[0][0];
    _Float16* Anxt = &As[1][0]; _Float16* Bnxt = &Bs[1][0];

#define DMA_CHUNK(K0, DST)                                                        \
    {                                                                             \
        const _Float16* gw = gwbase + (K0) + goff;                                \
        _Float16* lB = (DST) + ldsoff;                                            \
        _Pragma("unroll")                                                         \
        for (int r = 0; r < 4; ++r)                                               \
            __builtin_amdgcn_global_load_lds(GPTR(gw + r * 8 * 2048),             \
                                             LPTR(lB + r * 8 * 64), 16, 0, 0);    \
    }

#define VGEN_CHUNK(K0, DST)                                                       \
    {                                                                             \
        const int pg = ((K0) >> 1) + 2 * q;                                       \
        float4 t0 = Atab[pg], t1 = Atab[pg + 1];                                  \
        float2 ab0 = make_float2(t0.x, t0.y), ab1 = make_float2(t1.x, t1.y);      \
        float s, c;                                                               \
        float mg = __expf(t0.z * l0f);                                            \
        float x  = t0.w * l0f; x -= rintf(x); __sincosf(x * TWOPI, &s, &c);       \
        float2 v0 = make_float2(mg * c, mg * s);                                  \
        mg = __expf(t1.z * l0f);                                                  \
        x  = t1.w * l0f; x -= rintf(x); __sincosf(x * TWOPI, &s, &c);             \
        float2 v1 = make_float2(mg * c, mg * s);                                  \
        _Pragma("unroll")                                                         \
        for (int j = 0; j < 4; ++j) {                                             \
            int n0 = 2 * (llq + j);                                               \
            H2U h0u, h1u, h2u, h3u;                                               \
            h0u.h = __float22half2_rn(make_float2(v0.x, -v0.y));                  \
            h1u.h = __float22half2_rn(make_float2(v1.x, -v1.y));                  \
            h2u.h = __float22half2_rn(make_float2(v0.y, v0.x));                   \
            h3u.h = __float22half2_rn(make_float2(v1.y, v1.x));                   \
            int e0 = n0 * 64 + ((grp ^ (n0 & 7)) << 3) + sub;                     \
            int e1 = (n0 + 1) * 64 + ((grp ^ ((n0 + 1) & 7)) << 3) + sub;         \
            *(uint2*)((DST) + e0) = make_uint2(h0u.u, h1u.u);                     \
            *(uint2*)((DST) + e1) = make_uint2(h2u.u, h3u.u);                     \
            if (j < 3) { v0 = cmulf(v0, ab0); v1 = cmulf(v1, ab1); }              \
        }                                                                         \
    }

    // ---- prologue: Atab visible; producers fill chunk 0 ----
    __syncthreads();
    if (producer) {
        DMA_CHUNK(0, Acur)
        VGEN_CHUNK(0, Bcur)
        asm volatile("s_waitcnt vmcnt(0) lgkmcnt(0)" ::: "memory");
    }
    __builtin_amdgcn_sched_barrier(0);
    __builtin_amdgcn_s_barrier();        // chunk 0 published
    __builtin_amdgcn_sched_barrier(0);

    for (int kk = 0; kk < 32; ++kk) {
        if (producer) {
            if (kk < 31) {
                DMA_CHUNK((kk + 1) * BK, Anxt)      // issue first: max flight time
                VGEN_CHUNK((kk + 1) * BK, Bnxt)
                asm volatile("s_waitcnt vmcnt(0) lgkmcnt(0)" ::: "memory");
            }
        } else {
            #pragma unroll
            for (int ks = 0; ks < 2; ++ks) {
                f16x8 af[4], bf[4];
                const int g = ks * 4 + (lane >> 4);
                #pragma unroll
                for (int t = 0; t < 4; ++t) {
                    int m = wm * 64 + t * 16 + (lane & 15);
                    af[t] = *(const f16x8*)(Acur + m * 64 + ((g ^ (m & 7)) << 3));
                    int n = wn * 64 + t * 16 + (lane & 15);
                    bf[t] = *(const f16x8*)(Bcur + n * 64 + ((g ^ (n & 7)) << 3));
                }
                __builtin_amdgcn_s_setprio(1);
                #pragma unroll
                for (int mt = 0; mt < 4; ++mt)
                    #pragma unroll
                    for (int nt = 0; nt < 4; ++nt)
                        acc[mt][nt] = __builtin_amdgcn_mfma_f32_16x16x32_f16(
                            af[mt], bf[nt], acc[mt][nt], 0, 0, 0);
                __builtin_amdgcn_s_setprio(0);
            }
        }
        __builtin_amdgcn_sched_barrier(0);
        __builtin_amdgcn_s_barrier();    // consumers done with cur; nxt published
        __builtin_amdgcn_sched_barrier(0);

        _Float16* tA = Acur; Acur = Anxt; Anxt = tA;
        _Float16* tB = Bcur; Bcur = Bnxt; Bnxt = tB;
    }

    // ---- epilogue (consumers only): C/D layout col=lane&15, row=(lane>>4)*4+r ----
    if (!producer) {
        #pragma unroll
        for (int mt = 0; mt < 4; ++mt) {
            #pragma unroll
            for (int nt = 0; nt < 4; ++nt) {
                int h = m0 + wm * 64 + mt * 16 + ((lane >> 4) << 2);
                int n = nb + wn * 64 + nt * 16 + (lane & 15);
                #pragma unroll
                for (int r = 0; r < 4; ++r)
                    out[(size_t)(h + r) * 32768 + n] = acc[mt][nt][r] * INV_WSCALE;
            }
        }
    }
#undef DMA_CHUNK
#undef VGEN_CHUNK
}

extern "C" void kernel_launch(void* const* d_in, const int* in_sizes, int n_in,
                              void* d_out, int out_size, void* d_ws, size_t ws_size,
                              hipStream_t stream) {
    const float* A = (const float*)d_in[0];   // (P, 2)
    const float* B = (const float*)d_in[1];   // (P, H, 2)
    const float* C = (const float*)d_in[2];   // (H, P, 2)
    float* out = (float*)d_out;               // (H, L, 2)
    __half* W2 = (__half*)d_ws;               // (256, 2048) fp16, 1 MB

    prep_kernel<<<dim3(128), dim3(256), 0, stream>>>(A, B, C, W2);
    vand_mfma_kernel<<<dim3(L_DIM * 2 / BN, H_DIM / BM), dim3(NT), 0, stream>>>(
        A, (const _Float16*)W2, out);
}